// Round 18
// baseline (1346.946 us; speedup 1.0000x reference)
//
#include <hip/hip_runtime.h>
#include <hip/hip_bf16.h>

// ---------------------------------------------------------------------------
// PointNet++ SetAbstraction MSG  (B=8, N=4096, S=1024, radii .1/.2, k 16/32)
// fps -> ballquery -> [G1(+stats fused) -> affine -> G2(MFMA,+stats+pool)] x2
//   -> wsplit -> F1(MFMA, pool-concat fused) -> affine -> F2(MFMA) -> affine
//   -> final write.
// FPS / ball-query distances use fp-contract OFF to bit-match the f32 ref.
// R6/R8: fps floor ~795us (declared structural). R12: g2 MFMA bf16-split
// verified (1386->1312). R13/R15: f-chain -> MFMA (f_mfma, 64-row blocks,
// grid(128,2)); pool_concat FUSED into F1 staging; cat buffer + 2 launches
// eliminated; per-branch pmin/pmax; wf1/wf2 bf16-split into dead y1 region.
// R15/R16/R17: compile fix only (affine-output locals renamed pa*/pb* --
// had collided with const input params b2_0/b2_1). Infra retries.
// Frag maps (verified R12): A row=lane&15, k=kg*32+8*(lane>>4)+e; B col=
// lane&15 same k; D row=(lane>>4)*4+j, col=lane&15.
// ---------------------------------------------------------------------------

#define DEV __device__ __forceinline__

typedef __attribute__((ext_vector_type(8))) short short8v;
typedef __attribute__((ext_vector_type(4))) float float4v;

DEV float d2_nofma(float ax, float ay, float az, float bx, float by, float bz) {
#pragma clang fp contract(off)
  float dx = ax - bx, dy = ay - by, dz = az - bz;
  float s = dx * dx + dy * dy;
  return s + dz * dz;
}

DEV unsigned long long u64max(unsigned long long a, unsigned long long b) {
  return a > b ? a : b;
}

DEV void bsplit(float x, short& h, short& l) {
  __hip_bfloat16 hb = __float2bfloat16(x);
  float hf = __bfloat162float(hb);
  __hip_bfloat16 lb = __float2bfloat16(x - hf);
  h = *reinterpret_cast<short*>(&hb);
  l = *reinterpret_cast<short*>(&lb);
}

// ------------------------------ FPS ----------------------------------------
__global__ __launch_bounds__(512) void fps_kernel(
    const float* __restrict__ xyz, int* __restrict__ idx_out,
    float* __restrict__ nx_ws, float* __restrict__ nx_out) {
  __shared__ float sp[4096 * 3];
  __shared__ int hist[1024];
  __shared__ unsigned long long cand[2][8];
  const int b = blockIdx.x, t = threadIdx.x;
  const int w = t >> 6;
  const float* P = xyz + (size_t)b * 12288;
  float px[8], py[8], pz[8], dd[8];
#pragma unroll
  for (int j = 0; j < 8; j++) {
    int pi = t * 8 + j;
    float x = P[pi * 3], y = P[pi * 3 + 1], z = P[pi * 3 + 2];
    px[j] = x; py[j] = y; pz[j] = z; dd[j] = 1e10f;
    sp[pi * 3] = x; sp[pi * 3 + 1] = y; sp[pi * 3 + 2] = z;
  }
  __syncthreads();
  int last = 0;
  for (int it = 0; it < 1024; ++it) {
    if (t == 0) hist[it] = last;
    if (it == 1023) break;
    float lx = sp[last * 3], ly = sp[last * 3 + 1], lz = sp[last * 3 + 2];
#pragma unroll
    for (int j = 0; j < 8; j++) {
      float d = d2_nofma(px[j], py[j], pz[j], lx, ly, lz);
      dd[j] = fminf(dd[j], d);  // matches jnp.minimum
    }
    float bv = fmaxf(fmaxf(fmaxf(dd[0], dd[1]), fmaxf(dd[2], dd[3])),
                     fmaxf(fmaxf(dd[4], dd[5]), fmaxf(dd[6], dd[7])));
    int bj = 7;
#pragma unroll
    for (int j = 6; j >= 0; j--) bj = (dd[j] == bv) ? j : bj;
    int bi = t * 8 + bj;
    unsigned long long p =
        ((unsigned long long)__float_as_uint(bv) << 32) |
        (unsigned int)(4095 - bi);
#define DPP_MAX_STEP(CTRL)                                                  \
    {                                                                       \
      int lo_ = (int)(unsigned int)(p & 0xffffffffull);                     \
      int hi_ = (int)(unsigned int)(p >> 32);                               \
      int olo_ = __builtin_amdgcn_update_dpp(0, lo_, CTRL, 0xf, 0xf, false);\
      int ohi_ = __builtin_amdgcn_update_dpp(0, hi_, CTRL, 0xf, 0xf, false);\
      unsigned long long q_ =                                               \
          ((unsigned long long)(unsigned int)ohi_ << 32) |                  \
          (unsigned int)olo_;                                               \
      if (q_ > p) p = q_;                                                   \
    }
    DPP_MAX_STEP(0xB1);   // quad_perm xor1
    DPP_MAX_STEP(0x4E);   // quad_perm xor2
    DPP_MAX_STEP(0x124);  // row_ror:4
    DPP_MAX_STEP(0x128);  // row_ror:8   -> row-of-16 max everywhere
    DPP_MAX_STEP(0x142);  // row_bcast15
    DPP_MAX_STEP(0x143);  // row_bcast31 -> lane 63 = wave max
#undef DPP_MAX_STEP
    const int buf = it & 1;
    if ((t & 63) == 63) cand[buf][w] = p;
    __syncthreads();
    unsigned long long c0 = cand[buf][0], c1 = cand[buf][1];
    unsigned long long c2 = cand[buf][2], c3 = cand[buf][3];
    unsigned long long c4 = cand[buf][4], c5 = cand[buf][5];
    unsigned long long c6 = cand[buf][6], c7 = cand[buf][7];
    unsigned long long best =
        u64max(u64max(u64max(c0, c1), u64max(c2, c3)),
               u64max(u64max(c4, c5), u64max(c6, c7)));
    last = 4095 - (int)(unsigned int)(best & 0xffffffffull);
  }
  __syncthreads();
  for (int i = t; i < 1024; i += 512) {
    int id = hist[i];
    idx_out[(size_t)b * 1024 + i] = id;
    float x = sp[id * 3], y = sp[id * 3 + 1], z = sp[id * 3 + 2];
    size_t o = ((size_t)b * 1024 + i) * 3;
    nx_ws[o] = x; nx_ws[o + 1] = y; nx_ws[o + 2] = z;
    nx_out[o] = x; nx_out[o + 1] = y; nx_out[o + 2] = z;
  }
}

// --------------------------- Ball query ------------------------------------
__global__ __launch_bounds__(256) void bq_kernel(
    const float* __restrict__ xyz, const float* __restrict__ nx,
    int* __restrict__ out0, int* __restrict__ out1) {
  const int wv = threadIdx.x >> 6, lane = threadIdx.x & 63;
  const int bs = blockIdx.x * 4 + wv;  // 8192 centers
  const int b = bs >> 10;
  const float* c = nx + (size_t)bs * 3;
  const float cx = c[0], cy = c[1], cz = c[2];
  const float* P = xyz + (size_t)b * 12288;
  const float rr0 = 0.1f * 0.1f, rr1 = 0.2f * 0.2f;
  int c0 = 0, c1 = 0, f0 = -1, f1 = -1;
  const unsigned long long below = (1ull << lane) - 1ull;
  for (int base = 0; base < 4096; base += 64) {
    int p = base + lane;
    float x = P[p * 3], y = P[p * 3 + 1], z = P[p * 3 + 2];
    float d2 = d2_nofma(cx, cy, cz, x, y, z);
    bool in0 = d2 < rr0, in1 = d2 < rr1;
    unsigned long long m0 = __ballot(in0), m1 = __ballot(in1);
    if (in0) {
      int slot = c0 + __popcll(m0 & below);
      if (slot < 16) out0[(size_t)bs * 16 + slot] = p;
    }
    if (in1) {
      int slot = c1 + __popcll(m1 & below);
      if (slot < 32) out1[(size_t)bs * 32 + slot] = p;
    }
    if (f0 < 0 && m0) f0 = base + __ffsll(m0) - 1;
    if (f1 < 0 && m1) f1 = base + __ffsll(m1) - 1;
    c0 += __popcll(m0);
    c1 += __popcll(m1);
    if (c0 >= 16 && c1 >= 32) break;
  }
  if (c0 < 16 && lane >= c0 && lane < 16) out0[(size_t)bs * 16 + lane] = f0;
  if (c1 < 32 && lane >= c1 && lane < 32) out1[(size_t)bs * 32 + lane] = f1;
}

// ----------------- w2 bf16-split prep (once per branch) ---------------------
__global__ __launch_bounds__(256) void w2split_kernel(
    const float* __restrict__ w, short* __restrict__ h,
    short* __restrict__ l) {
  int i = blockIdx.x * 256 + threadIdx.x;  // 32768 = 256*128
  short hb, lb;
  bsplit(w[i], hb, lb);
  h[i] = hb;
  l[i] = lb;
}

// ------- wf1+wf2 bf16 split (runs after g2<32>, outputs in dead y1) ---------
__global__ __launch_bounds__(256) void wsplit2_kernel(
    const float* __restrict__ wa, int na, const float* __restrict__ wb,
    short* __restrict__ ha, short* __restrict__ la, short* __restrict__ hb,
    short* __restrict__ lb) {
  int i = blockIdx.x * 256 + threadIdx.x;  // na + nb total
  short h, l;
  if (i < na) {
    bsplit(wa[i], h, l);
    ha[i] = h; la[i] = l;
  } else {
    int j = i - na;
    bsplit(wb[j], h, l);
    hb[j] = h; lb[j] = l;
  }
}

// ------ G1: gather + GEMM (K=67,N=128) + FUSED column stats partials --------
template <int KS>
__global__ __launch_bounds__(256) void g1_kernel(
    const float* __restrict__ xyz, const float* __restrict__ feat,
    const float* __restrict__ nx, const int* __restrict__ idx,
    const float* __restrict__ w1, float* __restrict__ y1,
    float* __restrict__ statp) {
  __shared__ float At[34][132];
  __shared__ float Bt[34][132];
  const int t = threadIdx.x;
  const int g0 = blockIdx.x * 128;
  const int tx = t & 15, ty = t >> 4;
  const int r = t >> 1, half = t & 1;
  const int g = g0 + r;
  const int bs = g / KS;
  const int b = bs >> 10;
  const int id = idx[g];
  const float* fp = feat + ((size_t)(b * 4096 + id)) * 64;
  float rel0 = 0, rel1 = 0, rel2 = 0;
  if (half == 0) {
    const float* cp = nx + (size_t)bs * 3;
    const float* pp = xyz + ((size_t)(b * 4096 + id)) * 3;
    rel0 = pp[0] - cp[0]; rel1 = pp[1] - cp[1]; rel2 = pp[2] - cp[2];
  }
  float acc[8][8];
#pragma unroll
  for (int i = 0; i < 8; i++)
#pragma unroll
    for (int j = 0; j < 8; j++) acc[i][j] = 0.f;

#pragma unroll
  for (int kc = 0; kc < 2; ++kc) {
    const int kb = kc * 34;
    const int kn = kc ? 33 : 34;
    {
      int c0 = half * 17;
      int cn = half ? (kn - 17) : 17;
      for (int u = 0; u < cn; u++) {
        int cabs = kb + c0 + u;
        float v;
        if (cabs < 3) v = (cabs == 0) ? rel0 : ((cabs == 1) ? rel1 : rel2);
        else v = fp[cabs - 3];
        At[c0 + u][r] = v;
      }
    }
    {
      int o = t >> 1;
      const float* wp = w1 + (size_t)o * 67;
      int c0 = half * 17;
      int cn = half ? (kn - 17) : 17;
      for (int u = 0; u < cn; u++) Bt[c0 + u][o] = wp[kb + c0 + u];
    }
    __syncthreads();
#pragma unroll 4
    for (int k = 0; k < kn; k++) {
      float4 a0 = *(const float4*)&At[k][ty * 4];
      float4 a1 = *(const float4*)&At[k][ty * 4 + 64];
      float4 b0 = *(const float4*)&Bt[k][tx * 4];
      float4 b1 = *(const float4*)&Bt[k][tx * 4 + 64];
      float av[8] = {a0.x, a0.y, a0.z, a0.w, a1.x, a1.y, a1.z, a1.w};
      float bv[8] = {b0.x, b0.y, b0.z, b0.w, b1.x, b1.y, b1.z, b1.w};
#pragma unroll
      for (int i = 0; i < 8; i++)
#pragma unroll
        for (int j = 0; j < 8; j++) acc[i][j] = fmaf(av[i], bv[j], acc[i][j]);
    }
    __syncthreads();
  }
#pragma unroll
  for (int i = 0; i < 8; i++) {
    int R = ty * 4 + (i & 3) + ((i >> 2) << 6);
    float4 s0 = {acc[i][0], acc[i][1], acc[i][2], acc[i][3]};
    float4 s1 = {acc[i][4], acc[i][5], acc[i][6], acc[i][7]};
    *(float4*)&y1[((size_t)(g0 + R)) * 128 + tx * 4] = s0;
    *(float4*)&y1[((size_t)(g0 + R)) * 128 + tx * 4 + 64] = s1;
  }
  float s8[8], q8[8];
#pragma unroll
  for (int j = 0; j < 8; j++) {
    float s = 0, q = 0;
#pragma unroll
    for (int i = 0; i < 8; i++) {
      float v = acc[i][j];
      s += v;
      q = fmaf(v, v, q);
    }
    s += __shfl_xor(s, 16); s += __shfl_xor(s, 32);
    q += __shfl_xor(q, 16); q += __shfl_xor(q, 32);
    s8[j] = s; q8[j] = q;
  }
  float* red = &At[0][0];
  const int wvx = t >> 6;
  if ((t & 63) < 16) {
#pragma unroll
    for (int j = 0; j < 8; j++) {
      int col = tx * 4 + (j & 3) + ((j >> 2) << 6);
      red[wvx * 128 + col] = s8[j];
      red[512 + wvx * 128 + col] = q8[j];
    }
  }
  __syncthreads();
  if (t < 128) {
    float s = red[t] + red[128 + t] + red[256 + t] + red[384 + t];
    float q = red[512 + t] + red[640 + t] + red[768 + t] + red[896 + t];
    statp[(size_t)blockIdx.x * 256 + t] = s;
    statp[(size_t)blockIdx.x * 256 + 128 + t] = q;
  }
}

// ---- G2 (MFMA bf16-split): affine+relu -> GEMM (K=128,N=256) + stats + pool
template <int KS>
__global__ __launch_bounds__(256, 2) void g2_kernel(
    const float* __restrict__ y1, const short* __restrict__ w2h,
    const short* __restrict__ w2l, const float* __restrict__ a1,
    const float* __restrict__ b1, float* __restrict__ pmin,
    float* __restrict__ pmax, float* __restrict__ statp) {
  __shared__ __align__(16) short Abuf[2][128][136];  // [h/l][row][k padded]
  const int t = threadIdx.x;
  const int wv = t >> 6, lane = t & 63;
  const int g0 = blockIdx.x * 128;

  {
    const int r = t >> 1, half = t & 1;
    const float* arow = y1 + (size_t)(g0 + r) * 128 + half * 64;
#pragma unroll
    for (int q = 0; q < 8; q++) {
      float4 v0 = *(const float4*)&arow[q * 8];
      float4 v1 = *(const float4*)&arow[q * 8 + 4];
      float vv[8] = {v0.x, v0.y, v0.z, v0.w, v1.x, v1.y, v1.z, v1.w};
      short8v h8, l8;
#pragma unroll
      for (int e = 0; e < 8; e++) {
        int cabs = half * 64 + q * 8 + e;
        float x = fmaxf(fmaf(a1[cabs], vv[e], b1[cabs]), 0.f);
        short hh, ll;
        bsplit(x, hh, ll);
        h8[e] = hh; l8[e] = ll;
      }
      *(short8v*)&Abuf[0][r][half * 64 + q * 8] = h8;
      *(short8v*)&Abuf[1][r][half * 64 + q * 8] = l8;
    }
  }
  __syncthreads();

  const int kgo = (lane >> 4) * 8;
  short8v ahf[2][4], alf[2][4];
#pragma unroll
  for (int mt = 0; mt < 2; mt++)
#pragma unroll
    for (int kg = 0; kg < 4; kg++) {
      int rr = wv * 32 + mt * 16 + (lane & 15);
      ahf[mt][kg] = *(const short8v*)&Abuf[0][rr][kg * 32 + kgo];
      alf[mt][kg] = *(const short8v*)&Abuf[1][rr][kg * 32 + kgo];
    }
  __syncthreads();

  float4v acc[2][16];
#pragma unroll
  for (int mt = 0; mt < 2; mt++)
#pragma unroll
    for (int nt = 0; nt < 16; nt++) acc[mt][nt] = (float4v){0.f, 0.f, 0.f, 0.f};

#pragma unroll
  for (int kg = 0; kg < 4; kg++) {
#pragma unroll
    for (int nt = 0; nt < 16; nt++) {
      const int brow = nt * 16 + (lane & 15);
      const size_t bo = (size_t)brow * 128 + kg * 32 + kgo;
      short8v bh = *(const short8v*)&w2h[bo];
      short8v bl = *(const short8v*)&w2l[bo];
#pragma unroll
      for (int mt = 0; mt < 2; mt++) {
        acc[mt][nt] = __builtin_amdgcn_mfma_f32_16x16x32_bf16(
            ahf[mt][kg], bh, acc[mt][nt], 0, 0, 0);
        acc[mt][nt] = __builtin_amdgcn_mfma_f32_16x16x32_bf16(
            alf[mt][kg], bh, acc[mt][nt], 0, 0, 0);
        acc[mt][nt] = __builtin_amdgcn_mfma_f32_16x16x32_bf16(
            ahf[mt][kg], bl, acc[mt][nt], 0, 0, 0);
      }
    }
  }

  float* red = (float*)&Abuf[0][0][0];
#pragma unroll
  for (int nt = 0; nt < 16; nt++) {
    float s = 0, q = 0;
#pragma unroll
    for (int mt = 0; mt < 2; mt++)
#pragma unroll
      for (int j = 0; j < 4; j++) {
        float v = acc[mt][nt][j];
        s += v;
        q = fmaf(v, v, q);
      }
    s += __shfl_xor(s, 16); s += __shfl_xor(s, 32);
    q += __shfl_xor(q, 16); q += __shfl_xor(q, 32);
    if (lane < 16) {
      red[wv * 256 + nt * 16 + lane] = s;
      red[1024 + wv * 256 + nt * 16 + lane] = q;
    }
  }
  __syncthreads();
  {
    float s = red[t] + red[256 + t] + red[512 + t] + red[768 + t];
    float q = red[1024 + t] + red[1280 + t] + red[1536 + t] + red[1792 + t];
    statp[(size_t)blockIdx.x * 512 + t] = s;
    statp[(size_t)blockIdx.x * 512 + 256 + t] = q;
  }

  if (KS == 32) {
#pragma unroll
    for (int nt = 0; nt < 16; nt++) {
      float mn = acc[0][nt][0], mx = acc[0][nt][0];
#pragma unroll
      for (int mt = 0; mt < 2; mt++)
#pragma unroll
        for (int j = 0; j < 4; j++) {
          float v = acc[mt][nt][j];
          mn = fminf(mn, v);
          mx = fmaxf(mx, v);
        }
      mn = fminf(mn, __shfl_xor(mn, 16)); mn = fminf(mn, __shfl_xor(mn, 32));
      mx = fmaxf(mx, __shfl_xor(mx, 16)); mx = fmaxf(mx, __shfl_xor(mx, 32));
      if (lane < 16) {
        size_t o = (size_t)(blockIdx.x * 4 + wv) * 256 + nt * 16 + lane;
        pmin[o] = mn;
        pmax[o] = mx;
      }
    }
  } else {
#pragma unroll
    for (int mt = 0; mt < 2; mt++)
#pragma unroll
      for (int nt = 0; nt < 16; nt++) {
        float mn = acc[mt][nt][0], mx = acc[mt][nt][0];
#pragma unroll
        for (int j = 1; j < 4; j++) {
          float v = acc[mt][nt][j];
          mn = fminf(mn, v);
          mx = fmaxf(mx, v);
        }
        mn = fminf(mn, __shfl_xor(mn, 16)); mn = fminf(mn, __shfl_xor(mn, 32));
        mx = fmaxf(mx, __shfl_xor(mx, 16)); mx = fmaxf(mx, __shfl_xor(mx, 32));
        if (lane < 16) {
          size_t o = (size_t)(blockIdx.x * 8 + wv * 2 + mt) * 256 + nt * 16 + lane;
          pmin[o] = mn;
          pmax[o] = mx;
        }
      }
  }
}

// ---- F chain (MFMA bf16-split): 64-row blocks, grid(128,2); MODE 0 = F1
// (A = fused pool_concat from per-branch pmin/pmax + affine), MODE 1 = F2
// (A = affine+relu of src). Stats fused. Frag maps as g2 (mt=1).
template <int MODE>
__global__ __launch_bounds__(256, 4) void f_mfma(
    const float* __restrict__ src,
    const float* __restrict__ pmin0, const float* __restrict__ pmax0,
    const float* __restrict__ pmin1, const float* __restrict__ pmax1,
    const float* __restrict__ aa0, const float* __restrict__ bb0,
    const float* __restrict__ aa1, const float* __restrict__ bb1,
    const short* __restrict__ wh, const short* __restrict__ wl,
    float* __restrict__ Y, float* __restrict__ statp) {
  constexpr int K = MODE ? 256 : 512;
  constexpr int NCH = K / 128;
  __shared__ __align__(16) short Abuf[2][64][136];
  const int t = threadIdx.x;
  const int wv = t >> 6, lane = t & 63;
  const int g0 = blockIdx.x * 64, cb = blockIdx.y;
  const int kgo = (lane >> 4) * 8;

  float4v acc[8];
#pragma unroll
  for (int nt = 0; nt < 8; nt++) acc[nt] = (float4v){0.f, 0.f, 0.f, 0.f};

  for (int kc = 0; kc < NCH; kc++) {
    // ---- stage A chunk: thread t -> row t>>2, k-segment (t&3)*32..+31
    {
      const int r = t >> 2, seg = t & 3;
      const int row = g0 + r;
#pragma unroll
      for (int q = 0; q < 4; q++) {
        const int c0 = kc * 128 + seg * 32 + q * 8;  // abs channel base
        float v[8];
        if constexpr (MODE == 0) {
          const int br = c0 >> 8;
          const int cc0 = c0 & 255;
          const float* pa = br ? aa1 : aa0;
          const float* pb = br ? bb1 : bb0;
          const float* pmn = br ? pmin1 : pmin0;
          const float* pmx = br ? pmax1 : pmax0;
          float4 mn0 = *(const float4*)&pmn[(size_t)row * 256 + cc0];
          float4 mn1 = *(const float4*)&pmn[(size_t)row * 256 + cc0 + 4];
          float4 mx0 = *(const float4*)&pmx[(size_t)row * 256 + cc0];
          float4 mx1 = *(const float4*)&pmx[(size_t)row * 256 + cc0 + 4];
          float mns[8] = {mn0.x, mn0.y, mn0.z, mn0.w, mn1.x, mn1.y, mn1.z, mn1.w};
          float mxs[8] = {mx0.x, mx0.y, mx0.z, mx0.w, mx1.x, mx1.y, mx1.z, mx1.w};
#pragma unroll
          for (int e = 0; e < 8; e++) {
            float a = pa[cc0 + e];
            float ext = (a > 0.f) ? mxs[e] : mns[e];
            v[e] = fmaxf(fmaf(a, ext, pb[cc0 + e]), 0.f);
          }
        } else {
          float4 s0 = *(const float4*)&src[(size_t)row * 256 + c0];
          float4 s1 = *(const float4*)&src[(size_t)row * 256 + c0 + 4];
          float ss[8] = {s0.x, s0.y, s0.z, s0.w, s1.x, s1.y, s1.z, s1.w};
#pragma unroll
          for (int e = 0; e < 8; e++)
            v[e] = fmaxf(fmaf(aa0[c0 + e], ss[e], bb0[c0 + e]), 0.f);
        }
        short8v h8, l8;
#pragma unroll
        for (int e = 0; e < 8; e++) {
          short hh, ll;
          bsplit(v[e], hh, ll);
          h8[e] = hh; l8[e] = ll;
        }
        *(short8v*)&Abuf[0][r][seg * 32 + q * 8] = h8;
        *(short8v*)&Abuf[1][r][seg * 32 + q * 8] = l8;
      }
    }
    __syncthreads();
    // ---- A fragments for this chunk
    const int rr = wv * 16 + (lane & 15);
    short8v ah[4], al[4];
#pragma unroll
    for (int kg = 0; kg < 4; kg++) {
      ah[kg] = *(const short8v*)&Abuf[0][rr][kg * 32 + kgo];
      al[kg] = *(const short8v*)&Abuf[1][rr][kg * 32 + kgo];
    }
    __syncthreads();
    // ---- MFMA
#pragma unroll
    for (int kg = 0; kg < 4; kg++) {
#pragma unroll
      for (int nt = 0; nt < 8; nt++) {
        const int brow = cb * 128 + nt * 16 + (lane & 15);
        const size_t bo = (size_t)brow * K + kc * 128 + kg * 32 + kgo;
        short8v bh = *(const short8v*)&wh[bo];
        short8v bl = *(const short8v*)&wl[bo];
        acc[nt] = __builtin_amdgcn_mfma_f32_16x16x32_bf16(ah[kg], bh, acc[nt], 0, 0, 0);
        acc[nt] = __builtin_amdgcn_mfma_f32_16x16x32_bf16(al[kg], bh, acc[nt], 0, 0, 0);
        acc[nt] = __builtin_amdgcn_mfma_f32_16x16x32_bf16(ah[kg], bl, acc[nt], 0, 0, 0);
      }
    }
  }

  // ---- store D: row = g0 + wv*16 + (lane>>4)*4 + j, col = cb*128+nt*16+(lane&15)
#pragma unroll
  for (int nt = 0; nt < 8; nt++) {
#pragma unroll
    for (int j = 0; j < 4; j++) {
      int row = g0 + wv * 16 + (lane >> 4) * 4 + j;
      int col = cb * 128 + nt * 16 + (lane & 15);
      Y[(size_t)row * 256 + col] = acc[nt][j];
    }
  }

  // ---- stats: per-column sum/sq over this block's 64 rows
  float* red = (float*)&Abuf[0][0][0];  // [4][128] sum @0, sq @512
#pragma unroll
  for (int nt = 0; nt < 8; nt++) {
    float s = 0, q = 0;
#pragma unroll
    for (int j = 0; j < 4; j++) {
      float v = acc[nt][j];
      s += v;
      q = fmaf(v, v, q);
    }
    s += __shfl_xor(s, 16); s += __shfl_xor(s, 32);
    q += __shfl_xor(q, 16); q += __shfl_xor(q, 32);
    if (lane < 16) {
      red[wv * 128 + nt * 16 + lane] = s;
      red[512 + wv * 128 + nt * 16 + lane] = q;
    }
  }
  __syncthreads();
  if (t < 128) {
    float s = red[t] + red[128 + t] + red[256 + t] + red[384 + t];
    float q = red[512 + t] + red[640 + t] + red[768 + t] + red[896 + t];
    statp[(size_t)blockIdx.x * 512 + cb * 128 + t] = s;
    statp[(size_t)blockIdx.x * 512 + 256 + cb * 128 + t] = q;
  }
}

// ------------- reduce partials -> per-channel affine (a,b) ------------------
__global__ __launch_bounds__(256) void finalize_affine(
    const float* __restrict__ statp, int nb, float invM,
    const float* __restrict__ gamma, const float* __restrict__ beta,
    float* __restrict__ aout, float* __restrict__ bout, int N) {
  const int c = blockIdx.x;
  const int t = threadIdx.x;
  float s = 0, q = 0;
  for (int i = t; i < nb; i += 256) {
    s += statp[(size_t)i * 2 * N + c];
    q += statp[(size_t)i * 2 * N + N + c];
  }
#pragma unroll
  for (int m = 1; m <= 32; m <<= 1) {
    s += __shfl_xor(s, m);
    q += __shfl_xor(q, m);
  }
  __shared__ float rs[4], rq[4];
  if ((t & 63) == 0) { rs[t >> 6] = s; rq[t >> 6] = q; }
  __syncthreads();
  if (t == 0) {
    s = rs[0] + rs[1] + rs[2] + rs[3];
    q = rq[0] + rq[1] + rq[2] + rq[3];
    float mean = s * invM;
    float var = q * invM - mean * mean;
    float ia = gamma[c] * rsqrtf(var + 1e-5f);
    aout[c] = ia;
    bout[c] = beta[c] - mean * ia;
  }
}

// ------------------------------ final write --------------------------------
__global__ __launch_bounds__(256) void final_write(
    const float* __restrict__ y, const float* __restrict__ a,
    const float* __restrict__ b, float* __restrict__ out) {
  int i = blockIdx.x * 256 + threadIdx.x;
  int c = i & 255;
  out[i] = fmaxf(fmaf(a[c], y[i], b[c]), 0.f);
}

// ---------------------------------------------------------------------------
// ws layout (float offsets)
static const size_t OFF_IDXFPS = 0;         //  8192 (int)
static const size_t OFF_NEWXYZ = 8192;      // 24576
static const size_t OFF_IDX0 = 32768;       // 131072 (int)
static const size_t OFF_IDX1 = 163840;      // 262144 (int)
static const size_t OFF_Y1 = 425984;        // 33554432 (wf splits live here
                                            //  after g2<32>)
static const size_t OFF_PMIN0 = 33980416;   // 2097152
static const size_t OFF_PMAX0 = 36077568;   // 2097152
static const size_t OFF_STATP = 38174720;   // 1048576
static const size_t OFF_PM1 = 39223296;     // 4194304 (old cat: pmin1+pmax1)
static const size_t OFF_YF1 = 43417600;     // 2097152 (w2 splits live here
                                            //  until f_mfma<0> runs)
static const size_t OFF_YF2 = 45514752;     // 2097152
static const size_t OFF_AFF = 47611904;     // 2304

extern "C" void kernel_launch(void* const* d_in, const int* in_sizes, int n_in,
                              void* d_out, int out_size, void* d_ws,
                              size_t ws_size, hipStream_t stream) {
  const float* xyz = (const float*)d_in[0];
  const float* feat = (const float*)d_in[1];
  const float* w1_0 = (const float*)d_in[2];
  const float* g1_0 = (const float*)d_in[3];
  const float* b1_0 = (const float*)d_in[4];
  const float* w2_0 = (const float*)d_in[5];
  const float* g2_0 = (const float*)d_in[6];
  const float* b2_0 = (const float*)d_in[7];
  const float* w1_1 = (const float*)d_in[8];
  const float* g1_1 = (const float*)d_in[9];
  const float* b1_1 = (const float*)d_in[10];
  const float* w2_1 = (const float*)d_in[11];
  const float* g2_1 = (const float*)d_in[12];
  const float* b2_1 = (const float*)d_in[13];
  const float* wf1 = (const float*)d_in[14];
  const float* gf1 = (const float*)d_in[15];
  const float* bf1 = (const float*)d_in[16];
  const float* wf2 = (const float*)d_in[17];
  const float* gf2 = (const float*)d_in[18];
  const float* bf2 = (const float*)d_in[19];

  float* out = (float*)d_out;
  float* ws = (float*)d_ws;

  int* idxfps = (int*)(ws + OFF_IDXFPS);
  float* nx = ws + OFF_NEWXYZ;
  int* idx0 = (int*)(ws + OFF_IDX0);
  int* idx1 = (int*)(ws + OFF_IDX1);
  float* y1 = ws + OFF_Y1;
  float* pmin0 = ws + OFF_PMIN0;
  float* pmax0 = ws + OFF_PMAX0;
  float* statp = ws + OFF_STATP;
  float* pmin1 = ws + OFF_PM1;
  float* pmax1 = pmin1 + 2097152;
  float* yf1 = ws + OFF_YF1;
  float* yf2 = ws + OFF_YF2;
  // affine scratch (renamed: pa*/pb* to avoid collision with input params)
  float* pa1 = ws + OFF_AFF;
  float* pb1 = pa1 + 128;
  float* pa2_0 = pb1 + 128;
  float* pb2_0 = pa2_0 + 256;
  float* pa2_1 = pb2_0 + 256;
  float* pb2_1 = pa2_1 + 256;
  float* paf1 = pb2_1 + 256;
  float* pbf1 = paf1 + 256;
  float* paf2 = pbf1 + 256;
  float* pbf2 = paf2 + 256;
  // w2 bf16 splits in the (idle until f_mfma<0>) yf1 region:
  short* w2h0 = (short*)yf1;            // 32768 shorts each
  short* w2l0 = w2h0 + 32768;
  short* w2h1 = w2l0 + 32768;
  short* w2l1 = w2h1 + 32768;
  // wf splits in the (dead after g2<32>) y1 region:
  short* wf1h = (short*)y1;             // 131072 shorts
  short* wf1l = wf1h + 131072;
  short* wf2h = wf1l + 131072;          // 65536 shorts
  short* wf2l = wf2h + 65536;

  w2split_kernel<<<128, 256, 0, stream>>>(w2_0, w2h0, w2l0);
  w2split_kernel<<<128, 256, 0, stream>>>(w2_1, w2h1, w2l1);
  fps_kernel<<<8, 512, 0, stream>>>(xyz, idxfps, nx, out);
  bq_kernel<<<2048, 256, 0, stream>>>(xyz, nx, idx0, idx1);

  // branch 0 (r=0.1, k=16): M=131072
  g1_kernel<16><<<1024, 256, 0, stream>>>(xyz, feat, nx, idx0, w1_0, y1, statp);
  finalize_affine<<<128, 256, 0, stream>>>(statp, 1024, 1.f / 131072.f, g1_0, b1_0, pa1, pb1, 128);
  g2_kernel<16><<<1024, 256, 0, stream>>>(y1, w2h0, w2l0, pa1, pb1, pmin0, pmax0, statp);
  finalize_affine<<<256, 256, 0, stream>>>(statp, 1024, 1.f / 131072.f, g2_0, b2_0, pa2_0, pb2_0, 256);

  // branch 1 (r=0.2, k=32): M=262144
  g1_kernel<32><<<2048, 256, 0, stream>>>(xyz, feat, nx, idx1, w1_1, y1, statp);
  finalize_affine<<<128, 256, 0, stream>>>(statp, 2048, 1.f / 262144.f, g1_1, b1_1, pa1, pb1, 128);
  g2_kernel<32><<<2048, 256, 0, stream>>>(y1, w2h1, w2l1, pa1, pb1, pmin1, pmax1, statp);
  finalize_affine<<<256, 256, 0, stream>>>(statp, 2048, 1.f / 262144.f, g2_1, b2_1, pa2_1, pb2_1, 256);

  // split wf1/wf2 into dead y1 region; then fuse MLP (pool_concat fused
  // into f_mfma<0>'s staging)
  wsplit2_kernel<<<768, 256, 0, stream>>>(wf1, 131072, wf2, wf1h, wf1l, wf2h, wf2l);
  f_mfma<0><<<dim3(128, 2), 256, 0, stream>>>(
      nullptr, pmin0, pmax0, pmin1, pmax1, pa2_0, pb2_0, pa2_1, pb2_1,
      wf1h, wf1l, yf1, statp);
  finalize_affine<<<256, 256, 0, stream>>>(statp, 128, 1.f / 8192.f, gf1, bf1, paf1, pbf1, 256);
  f_mfma<1><<<dim3(128, 2), 256, 0, stream>>>(
      yf1, nullptr, nullptr, nullptr, nullptr, paf1, pbf1, nullptr, nullptr,
      wf2h, wf2l, yf2, statp);
  finalize_affine<<<256, 256, 0, stream>>>(statp, 128, 1.f / 8192.f, gf2, bf2, paf2, pbf2, 256);
  final_write<<<8192, 256, 0, stream>>>(yf2, paf2, pbf2, out + 24576);
}

// Round 21
// 1312.097 us; speedup vs baseline: 1.0266x; 1.0266x over previous
//
#include <hip/hip_runtime.h>
#include <hip/hip_bf16.h>

// ---------------------------------------------------------------------------
// PointNet++ SetAbstraction MSG  (B=8, N=4096, S=1024, radii .1/.2, k 16/32)
// fps -> ballquery -> [G1(+stats fused) -> affine -> G2(MFMA,+stats+pool)] x2
//   -> pool_concat -> F1(+stats) -> affine -> F2(+stats) -> final write.
// FPS / ball-query distances use fp-contract OFF to bit-match the f32 ref.
// R6/R8: fps floor ~795us (structural: barrier+issue+serial-select balanced).
// R12: g2 MFMA bf16-split verified (1386->1312; frag k-offset bug fixed).
// R13-R18: f-chain MFMA + pool_concat fusion REGRESSED (1347): scattered
// per-lane B rows beat fp32 f_kernel's coalesced loads at K<=512; reverted.
// This is the R12 best-measured configuration (1312us).
// Frag maps (verified): A row=lane&15, k=kg*32+8*(lane>>4)+e; B col=lane&15
// same k; D row=(lane>>4)*4+j, col=lane&15.
// ---------------------------------------------------------------------------

#define DEV __device__ __forceinline__

typedef __attribute__((ext_vector_type(8))) short short8v;
typedef __attribute__((ext_vector_type(4))) float float4v;

DEV float d2_nofma(float ax, float ay, float az, float bx, float by, float bz) {
#pragma clang fp contract(off)
  float dx = ax - bx, dy = ay - by, dz = az - bz;
  float s = dx * dx + dy * dy;
  return s + dz * dz;
}

DEV unsigned long long u64max(unsigned long long a, unsigned long long b) {
  return a > b ? a : b;
}

DEV void bsplit(float x, short& h, short& l) {
  __hip_bfloat16 hb = __float2bfloat16(x);
  float hf = __bfloat162float(hb);
  __hip_bfloat16 lb = __float2bfloat16(x - hf);
  h = *reinterpret_cast<short*>(&hb);
  l = *reinterpret_cast<short*>(&lb);
}

// ------------------------------ FPS ----------------------------------------
__global__ __launch_bounds__(512) void fps_kernel(
    const float* __restrict__ xyz, int* __restrict__ idx_out,
    float* __restrict__ nx_ws, float* __restrict__ nx_out) {
  __shared__ float sp[4096 * 3];
  __shared__ int hist[1024];
  __shared__ unsigned long long cand[2][8];
  const int b = blockIdx.x, t = threadIdx.x;
  const int w = t >> 6;
  const float* P = xyz + (size_t)b * 12288;
  float px[8], py[8], pz[8], dd[8];
#pragma unroll
  for (int j = 0; j < 8; j++) {
    int pi = t * 8 + j;
    float x = P[pi * 3], y = P[pi * 3 + 1], z = P[pi * 3 + 2];
    px[j] = x; py[j] = y; pz[j] = z; dd[j] = 1e10f;
    sp[pi * 3] = x; sp[pi * 3 + 1] = y; sp[pi * 3 + 2] = z;
  }
  __syncthreads();
  int last = 0;
  for (int it = 0; it < 1024; ++it) {
    if (t == 0) hist[it] = last;
    if (it == 1023) break;
    float lx = sp[last * 3], ly = sp[last * 3 + 1], lz = sp[last * 3 + 2];
#pragma unroll
    for (int j = 0; j < 8; j++) {
      float d = d2_nofma(px[j], py[j], pz[j], lx, ly, lz);
      dd[j] = fminf(dd[j], d);  // matches jnp.minimum
    }
    float bv = fmaxf(fmaxf(fmaxf(dd[0], dd[1]), fmaxf(dd[2], dd[3])),
                     fmaxf(fmaxf(dd[4], dd[5]), fmaxf(dd[6], dd[7])));
    int bj = 7;
#pragma unroll
    for (int j = 6; j >= 0; j--) bj = (dd[j] == bv) ? j : bj;
    int bi = t * 8 + bj;
    unsigned long long p =
        ((unsigned long long)__float_as_uint(bv) << 32) |
        (unsigned int)(4095 - bi);
#define DPP_MAX_STEP(CTRL)                                                  \
    {                                                                       \
      int lo_ = (int)(unsigned int)(p & 0xffffffffull);                     \
      int hi_ = (int)(unsigned int)(p >> 32);                               \
      int olo_ = __builtin_amdgcn_update_dpp(0, lo_, CTRL, 0xf, 0xf, false);\
      int ohi_ = __builtin_amdgcn_update_dpp(0, hi_, CTRL, 0xf, 0xf, false);\
      unsigned long long q_ =                                               \
          ((unsigned long long)(unsigned int)ohi_ << 32) |                  \
          (unsigned int)olo_;                                               \
      if (q_ > p) p = q_;                                                   \
    }
    DPP_MAX_STEP(0xB1);   // quad_perm xor1
    DPP_MAX_STEP(0x4E);   // quad_perm xor2
    DPP_MAX_STEP(0x124);  // row_ror:4
    DPP_MAX_STEP(0x128);  // row_ror:8   -> row-of-16 max everywhere
    DPP_MAX_STEP(0x142);  // row_bcast15
    DPP_MAX_STEP(0x143);  // row_bcast31 -> lane 63 = wave max
#undef DPP_MAX_STEP
    const int buf = it & 1;
    if ((t & 63) == 63) cand[buf][w] = p;
    __syncthreads();
    unsigned long long c0 = cand[buf][0], c1 = cand[buf][1];
    unsigned long long c2 = cand[buf][2], c3 = cand[buf][3];
    unsigned long long c4 = cand[buf][4], c5 = cand[buf][5];
    unsigned long long c6 = cand[buf][6], c7 = cand[buf][7];
    unsigned long long best =
        u64max(u64max(u64max(c0, c1), u64max(c2, c3)),
               u64max(u64max(c4, c5), u64max(c6, c7)));
    last = 4095 - (int)(unsigned int)(best & 0xffffffffull);
  }
  __syncthreads();
  for (int i = t; i < 1024; i += 512) {
    int id = hist[i];
    idx_out[(size_t)b * 1024 + i] = id;
    float x = sp[id * 3], y = sp[id * 3 + 1], z = sp[id * 3 + 2];
    size_t o = ((size_t)b * 1024 + i) * 3;
    nx_ws[o] = x; nx_ws[o + 1] = y; nx_ws[o + 2] = z;
    nx_out[o] = x; nx_out[o + 1] = y; nx_out[o + 2] = z;
  }
}

// --------------------------- Ball query ------------------------------------
__global__ __launch_bounds__(256) void bq_kernel(
    const float* __restrict__ xyz, const float* __restrict__ nx,
    int* __restrict__ out0, int* __restrict__ out1) {
  const int wv = threadIdx.x >> 6, lane = threadIdx.x & 63;
  const int bs = blockIdx.x * 4 + wv;  // 8192 centers
  const int b = bs >> 10;
  const float* c = nx + (size_t)bs * 3;
  const float cx = c[0], cy = c[1], cz = c[2];
  const float* P = xyz + (size_t)b * 12288;
  const float rr0 = 0.1f * 0.1f, rr1 = 0.2f * 0.2f;
  int c0 = 0, c1 = 0, f0 = -1, f1 = -1;
  const unsigned long long below = (1ull << lane) - 1ull;
  for (int base = 0; base < 4096; base += 64) {
    int p = base + lane;
    float x = P[p * 3], y = P[p * 3 + 1], z = P[p * 3 + 2];
    float d2 = d2_nofma(cx, cy, cz, x, y, z);
    bool in0 = d2 < rr0, in1 = d2 < rr1;
    unsigned long long m0 = __ballot(in0), m1 = __ballot(in1);
    if (in0) {
      int slot = c0 + __popcll(m0 & below);
      if (slot < 16) out0[(size_t)bs * 16 + slot] = p;
    }
    if (in1) {
      int slot = c1 + __popcll(m1 & below);
      if (slot < 32) out1[(size_t)bs * 32 + slot] = p;
    }
    if (f0 < 0 && m0) f0 = base + __ffsll(m0) - 1;
    if (f1 < 0 && m1) f1 = base + __ffsll(m1) - 1;
    c0 += __popcll(m0);
    c1 += __popcll(m1);
    if (c0 >= 16 && c1 >= 32) break;
  }
  if (c0 < 16 && lane >= c0 && lane < 16) out0[(size_t)bs * 16 + lane] = f0;
  if (c1 < 32 && lane >= c1 && lane < 32) out1[(size_t)bs * 32 + lane] = f1;
}

// ----------------- w2 bf16-split prep (once per branch) ---------------------
__global__ __launch_bounds__(256) void w2split_kernel(
    const float* __restrict__ w, short* __restrict__ h,
    short* __restrict__ l) {
  int i = blockIdx.x * 256 + threadIdx.x;  // 32768 = 256*128
  short hb, lb;
  bsplit(w[i], hb, lb);
  h[i] = hb;
  l[i] = lb;
}

// ------ G1: gather + GEMM (K=67,N=128) + FUSED column stats partials --------
template <int KS>
__global__ __launch_bounds__(256) void g1_kernel(
    const float* __restrict__ xyz, const float* __restrict__ feat,
    const float* __restrict__ nx, const int* __restrict__ idx,
    const float* __restrict__ w1, float* __restrict__ y1,
    float* __restrict__ statp) {
  __shared__ float At[34][132];
  __shared__ float Bt[34][132];
  const int t = threadIdx.x;
  const int g0 = blockIdx.x * 128;
  const int tx = t & 15, ty = t >> 4;
  const int r = t >> 1, half = t & 1;
  const int g = g0 + r;
  const int bs = g / KS;
  const int b = bs >> 10;
  const int id = idx[g];
  const float* fp = feat + ((size_t)(b * 4096 + id)) * 64;
  float rel0 = 0, rel1 = 0, rel2 = 0;
  if (half == 0) {
    const float* cp = nx + (size_t)bs * 3;
    const float* pp = xyz + ((size_t)(b * 4096 + id)) * 3;
    rel0 = pp[0] - cp[0]; rel1 = pp[1] - cp[1]; rel2 = pp[2] - cp[2];
  }
  float acc[8][8];
#pragma unroll
  for (int i = 0; i < 8; i++)
#pragma unroll
    for (int j = 0; j < 8; j++) acc[i][j] = 0.f;

#pragma unroll
  for (int kc = 0; kc < 2; ++kc) {
    const int kb = kc * 34;
    const int kn = kc ? 33 : 34;
    {
      int c0 = half * 17;
      int cn = half ? (kn - 17) : 17;
      for (int u = 0; u < cn; u++) {
        int cabs = kb + c0 + u;
        float v;
        if (cabs < 3) v = (cabs == 0) ? rel0 : ((cabs == 1) ? rel1 : rel2);
        else v = fp[cabs - 3];
        At[c0 + u][r] = v;
      }
    }
    {
      int o = t >> 1;
      const float* wp = w1 + (size_t)o * 67;
      int c0 = half * 17;
      int cn = half ? (kn - 17) : 17;
      for (int u = 0; u < cn; u++) Bt[c0 + u][o] = wp[kb + c0 + u];
    }
    __syncthreads();
#pragma unroll 4
    for (int k = 0; k < kn; k++) {
      float4 a0 = *(const float4*)&At[k][ty * 4];
      float4 a1 = *(const float4*)&At[k][ty * 4 + 64];
      float4 b0 = *(const float4*)&Bt[k][tx * 4];
      float4 b1 = *(const float4*)&Bt[k][tx * 4 + 64];
      float av[8] = {a0.x, a0.y, a0.z, a0.w, a1.x, a1.y, a1.z, a1.w};
      float bv[8] = {b0.x, b0.y, b0.z, b0.w, b1.x, b1.y, b1.z, b1.w};
#pragma unroll
      for (int i = 0; i < 8; i++)
#pragma unroll
        for (int j = 0; j < 8; j++) acc[i][j] = fmaf(av[i], bv[j], acc[i][j]);
    }
    __syncthreads();
  }
#pragma unroll
  for (int i = 0; i < 8; i++) {
    int R = ty * 4 + (i & 3) + ((i >> 2) << 6);
    float4 s0 = {acc[i][0], acc[i][1], acc[i][2], acc[i][3]};
    float4 s1 = {acc[i][4], acc[i][5], acc[i][6], acc[i][7]};
    *(float4*)&y1[((size_t)(g0 + R)) * 128 + tx * 4] = s0;
    *(float4*)&y1[((size_t)(g0 + R)) * 128 + tx * 4 + 64] = s1;
  }
  float s8[8], q8[8];
#pragma unroll
  for (int j = 0; j < 8; j++) {
    float s = 0, q = 0;
#pragma unroll
    for (int i = 0; i < 8; i++) {
      float v = acc[i][j];
      s += v;
      q = fmaf(v, v, q);
    }
    s += __shfl_xor(s, 16); s += __shfl_xor(s, 32);
    q += __shfl_xor(q, 16); q += __shfl_xor(q, 32);
    s8[j] = s; q8[j] = q;
  }
  float* red = &At[0][0];
  const int wvx = t >> 6;
  if ((t & 63) < 16) {
#pragma unroll
    for (int j = 0; j < 8; j++) {
      int col = tx * 4 + (j & 3) + ((j >> 2) << 6);
      red[wvx * 128 + col] = s8[j];
      red[512 + wvx * 128 + col] = q8[j];
    }
  }
  __syncthreads();
  if (t < 128) {
    float s = red[t] + red[128 + t] + red[256 + t] + red[384 + t];
    float q = red[512 + t] + red[640 + t] + red[768 + t] + red[896 + t];
    statp[(size_t)blockIdx.x * 256 + t] = s;
    statp[(size_t)blockIdx.x * 256 + 128 + t] = q;
  }
}

// ---- G2 (MFMA bf16-split): affine+relu -> GEMM (K=128,N=256) + stats + pool
template <int KS>
__global__ __launch_bounds__(256, 2) void g2_kernel(
    const float* __restrict__ y1, const short* __restrict__ w2h,
    const short* __restrict__ w2l, const float* __restrict__ a1,
    const float* __restrict__ b1, float* __restrict__ pmin,
    float* __restrict__ pmax, float* __restrict__ statp) {
  __shared__ __align__(16) short Abuf[2][128][136];  // [h/l][row][k padded]
  const int t = threadIdx.x;
  const int wv = t >> 6, lane = t & 63;
  const int g0 = blockIdx.x * 128;

  {
    const int r = t >> 1, half = t & 1;
    const float* arow = y1 + (size_t)(g0 + r) * 128 + half * 64;
#pragma unroll
    for (int q = 0; q < 8; q++) {
      float4 v0 = *(const float4*)&arow[q * 8];
      float4 v1 = *(const float4*)&arow[q * 8 + 4];
      float vv[8] = {v0.x, v0.y, v0.z, v0.w, v1.x, v1.y, v1.z, v1.w};
      short8v h8, l8;
#pragma unroll
      for (int e = 0; e < 8; e++) {
        int cabs = half * 64 + q * 8 + e;
        float x = fmaxf(fmaf(a1[cabs], vv[e], b1[cabs]), 0.f);
        short hh, ll;
        bsplit(x, hh, ll);
        h8[e] = hh; l8[e] = ll;
      }
      *(short8v*)&Abuf[0][r][half * 64 + q * 8] = h8;
      *(short8v*)&Abuf[1][r][half * 64 + q * 8] = l8;
    }
  }
  __syncthreads();

  const int kgo = (lane >> 4) * 8;
  short8v ahf[2][4], alf[2][4];
#pragma unroll
  for (int mt = 0; mt < 2; mt++)
#pragma unroll
    for (int kg = 0; kg < 4; kg++) {
      int rr = wv * 32 + mt * 16 + (lane & 15);
      ahf[mt][kg] = *(const short8v*)&Abuf[0][rr][kg * 32 + kgo];
      alf[mt][kg] = *(const short8v*)&Abuf[1][rr][kg * 32 + kgo];
    }
  __syncthreads();

  float4v acc[2][16];
#pragma unroll
  for (int mt = 0; mt < 2; mt++)
#pragma unroll
    for (int nt = 0; nt < 16; nt++) acc[mt][nt] = (float4v){0.f, 0.f, 0.f, 0.f};

#pragma unroll
  for (int kg = 0; kg < 4; kg++) {
#pragma unroll
    for (int nt = 0; nt < 16; nt++) {
      const int brow = nt * 16 + (lane & 15);
      const size_t bo = (size_t)brow * 128 + kg * 32 + kgo;
      short8v bh = *(const short8v*)&w2h[bo];
      short8v bl = *(const short8v*)&w2l[bo];
#pragma unroll
      for (int mt = 0; mt < 2; mt++) {
        acc[mt][nt] = __builtin_amdgcn_mfma_f32_16x16x32_bf16(
            ahf[mt][kg], bh, acc[mt][nt], 0, 0, 0);
        acc[mt][nt] = __builtin_amdgcn_mfma_f32_16x16x32_bf16(
            alf[mt][kg], bh, acc[mt][nt], 0, 0, 0);
        acc[mt][nt] = __builtin_amdgcn_mfma_f32_16x16x32_bf16(
            ahf[mt][kg], bl, acc[mt][nt], 0, 0, 0);
      }
    }
  }

  float* red = (float*)&Abuf[0][0][0];
#pragma unroll
  for (int nt = 0; nt < 16; nt++) {
    float s = 0, q = 0;
#pragma unroll
    for (int mt = 0; mt < 2; mt++)
#pragma unroll
      for (int j = 0; j < 4; j++) {
        float v = acc[mt][nt][j];
        s += v;
        q = fmaf(v, v, q);
      }
    s += __shfl_xor(s, 16); s += __shfl_xor(s, 32);
    q += __shfl_xor(q, 16); q += __shfl_xor(q, 32);
    if (lane < 16) {
      red[wv * 256 + nt * 16 + lane] = s;
      red[1024 + wv * 256 + nt * 16 + lane] = q;
    }
  }
  __syncthreads();
  {
    float s = red[t] + red[256 + t] + red[512 + t] + red[768 + t];
    float q = red[1024 + t] + red[1280 + t] + red[1536 + t] + red[1792 + t];
    statp[(size_t)blockIdx.x * 512 + t] = s;
    statp[(size_t)blockIdx.x * 512 + 256 + t] = q;
  }

  if (KS == 32) {
#pragma unroll
    for (int nt = 0; nt < 16; nt++) {
      float mn = acc[0][nt][0], mx = acc[0][nt][0];
#pragma unroll
      for (int mt = 0; mt < 2; mt++)
#pragma unroll
        for (int j = 0; j < 4; j++) {
          float v = acc[mt][nt][j];
          mn = fminf(mn, v);
          mx = fmaxf(mx, v);
        }
      mn = fminf(mn, __shfl_xor(mn, 16)); mn = fminf(mn, __shfl_xor(mn, 32));
      mx = fmaxf(mx, __shfl_xor(mx, 16)); mx = fmaxf(mx, __shfl_xor(mx, 32));
      if (lane < 16) {
        size_t o = (size_t)(blockIdx.x * 4 + wv) * 256 + nt * 16 + lane;
        pmin[o] = mn;
        pmax[o] = mx;
      }
    }
  } else {
#pragma unroll
    for (int mt = 0; mt < 2; mt++)
#pragma unroll
      for (int nt = 0; nt < 16; nt++) {
        float mn = acc[mt][nt][0], mx = acc[mt][nt][0];
#pragma unroll
        for (int j = 1; j < 4; j++) {
          float v = acc[mt][nt][j];
          mn = fminf(mn, v);
          mx = fmaxf(mx, v);
        }
        mn = fminf(mn, __shfl_xor(mn, 16)); mn = fminf(mn, __shfl_xor(mn, 32));
        mx = fmaxf(mx, __shfl_xor(mx, 16)); mx = fmaxf(mx, __shfl_xor(mx, 32));
        if (lane < 16) {
          size_t o = (size_t)(blockIdx.x * 8 + wv * 2 + mt) * 256 + nt * 16 + lane;
          pmin[o] = mn;
          pmax[o] = mx;
        }
      }
  }
}

// ------------- reduce partials -> per-channel affine (a,b) ------------------
__global__ __launch_bounds__(256) void finalize_affine(
    const float* __restrict__ statp, int nb, float invM,
    const float* __restrict__ gamma, const float* __restrict__ beta,
    float* __restrict__ aout, float* __restrict__ bout, int N) {
  const int c = blockIdx.x;
  const int t = threadIdx.x;
  float s = 0, q = 0;
  for (int i = t; i < nb; i += 256) {
    s += statp[(size_t)i * 2 * N + c];
    q += statp[(size_t)i * 2 * N + N + c];
  }
#pragma unroll
  for (int m = 1; m <= 32; m <<= 1) {
    s += __shfl_xor(s, m);
    q += __shfl_xor(q, m);
  }
  __shared__ float rs[4], rq[4];
  if ((t & 63) == 0) { rs[t >> 6] = s; rq[t >> 6] = q; }
  __syncthreads();
  if (t == 0) {
    s = rs[0] + rs[1] + rs[2] + rs[3];
    q = rq[0] + rq[1] + rq[2] + rq[3];
    float mean = s * invM;
    float var = q * invM - mean * mean;
    float ia = gamma[c] * rsqrtf(var + 1e-5f);
    aout[c] = ia;
    bout[c] = beta[c] - mean * ia;
  }
}

// --------- pooled minmax + affine -> concat activation [8192][512] ----------
__global__ __launch_bounds__(256) void pool_concat(
    const float* __restrict__ pmin, const float* __restrict__ pmax,
    const float* __restrict__ a2, const float* __restrict__ b2,
    float* __restrict__ cat, int off) {
  int i = blockIdx.x * 256 + threadIdx.x;
  int row = i >> 8, c = i & 255;
  float a = a2[c];
  float v = (a > 0.f) ? pmax[i] : pmin[i];  // max(relu(a*x+b)) = relu(a*ext+b)
  cat[(size_t)row * 512 + off + c] = fmaxf(fmaf(a, v, b2[c]), 0.f);
}

// ------ fuse GEMMs: M=8192, N=256 (2 col blocks of 128) + FUSED stats -------
template <bool AFF>
__global__ __launch_bounds__(256) void f_kernel(
    const float* __restrict__ A, const float* __restrict__ W,
    const float* __restrict__ ain, const float* __restrict__ bin,
    float* __restrict__ Y, int K, float* __restrict__ statp) {
  __shared__ float At[64][68];
  __shared__ float Bt[64][132];
  const int t = threadIdx.x, tx = t & 15, ty = t >> 4;
  const int g0 = blockIdx.x * 64, cb = blockIdx.y;
  float acc[4][8];
#pragma unroll
  for (int i = 0; i < 4; i++)
#pragma unroll
    for (int j = 0; j < 8; j++) acc[i][j] = 0.f;
  const int rA = t >> 2, qA = t & 3;
  const int oB = t >> 1, hB = t & 1;
  const float* arow = A + (size_t)(g0 + rA) * K + qA * 16;
  const float* wrow = W + (size_t)(cb * 128 + oB) * K + hB * 32;
  for (int kc = 0; kc < K; kc += 64) {
    {
#pragma unroll
      for (int q = 0; q < 4; q++) {
        float4 v = *(const float4*)&arow[kc + q * 4];
        float vv[4] = {v.x, v.y, v.z, v.w};
        if constexpr (AFF) {
          int c = kc + qA * 16 + q * 4;
#pragma unroll
          for (int e = 0; e < 4; e++)
            vv[e] = fmaxf(fmaf(ain[c + e], vv[e], bin[c + e]), 0.f);
        }
#pragma unroll
        for (int e = 0; e < 4; e++) At[qA * 16 + q * 4 + e][rA] = vv[e];
      }
    }
    {
#pragma unroll
      for (int q = 0; q < 8; q++) {
        float4 v = *(const float4*)&wrow[kc + q * 4];
        Bt[hB * 32 + q * 4 + 0][oB] = v.x;
        Bt[hB * 32 + q * 4 + 1][oB] = v.y;
        Bt[hB * 32 + q * 4 + 2][oB] = v.z;
        Bt[hB * 32 + q * 4 + 3][oB] = v.w;
      }
    }
    __syncthreads();
#pragma unroll 8
    for (int k = 0; k < 64; k++) {
      float4 a0 = *(const float4*)&At[k][ty * 4];
      float4 b0 = *(const float4*)&Bt[k][tx * 4];
      float4 b1 = *(const float4*)&Bt[k][tx * 4 + 64];
      float av[4] = {a0.x, a0.y, a0.z, a0.w};
      float bv[8] = {b0.x, b0.y, b0.z, b0.w, b1.x, b1.y, b1.z, b1.w};
#pragma unroll
      for (int i = 0; i < 4; i++)
#pragma unroll
        for (int j = 0; j < 8; j++) acc[i][j] = fmaf(av[i], bv[j], acc[i][j]);
    }
    __syncthreads();
  }
#pragma unroll
  for (int i = 0; i < 4; i++) {
    int R = g0 + ty * 4 + i;
    float4 s0 = {acc[i][0], acc[i][1], acc[i][2], acc[i][3]};
    float4 s1 = {acc[i][4], acc[i][5], acc[i][6], acc[i][7]};
    *(float4*)&Y[(size_t)R * 256 + cb * 128 + tx * 4] = s0;
    *(float4*)&Y[(size_t)R * 256 + cb * 128 + tx * 4 + 64] = s1;
  }
  float s8[8], q8[8];
#pragma unroll
  for (int j = 0; j < 8; j++) {
    float s = 0, q = 0;
#pragma unroll
    for (int i = 0; i < 4; i++) {
      float v = acc[i][j];
      s += v;
      q = fmaf(v, v, q);
    }
    s += __shfl_xor(s, 16); s += __shfl_xor(s, 32);
    q += __shfl_xor(q, 16); q += __shfl_xor(q, 32);
    s8[j] = s; q8[j] = q;
  }
  float* red = &At[0][0];
  const int wvx = t >> 6;
  if ((t & 63) < 16) {
#pragma unroll
    for (int j = 0; j < 8; j++) {
      int col = tx * 4 + (j & 3) + ((j >> 2) << 6);
      red[wvx * 128 + col] = s8[j];
      red[512 + wvx * 128 + col] = q8[j];
    }
  }
  __syncthreads();
  if (t < 128) {
    float s = red[t] + red[128 + t] + red[256 + t] + red[384 + t];
    float q = red[512 + t] + red[640 + t] + red[768 + t] + red[896 + t];
    statp[(size_t)blockIdx.x * 512 + cb * 128 + t] = s;
    statp[(size_t)blockIdx.x * 512 + 256 + cb * 128 + t] = q;
  }
}

// ------------------------------ final write --------------------------------
__global__ __launch_bounds__(256) void final_write(
    const float* __restrict__ y, const float* __restrict__ a,
    const float* __restrict__ b, float* __restrict__ out) {
  int i = blockIdx.x * 256 + threadIdx.x;
  int c = i & 255;
  out[i] = fmaxf(fmaf(a[c], y[i], b[c]), 0.f);
}

// ---------------------------------------------------------------------------
// ws layout (float offsets)
static const size_t OFF_IDXFPS = 0;         //  8192 (int)
static const size_t OFF_NEWXYZ = 8192;      // 24576
static const size_t OFF_IDX0 = 32768;       // 131072 (int)
static const size_t OFF_IDX1 = 163840;      // 262144 (int)
static const size_t OFF_Y1 = 425984;        // 33554432
static const size_t OFF_PMIN = 33980416;    // 2097152
static const size_t OFF_PMAX = 36077568;    // 2097152
static const size_t OFF_STATP = 38174720;   // 1048576
static const size_t OFF_CONCAT = 39223296;  // 4194304
static const size_t OFF_YF1 = 43417600;     // 2097152 (w2 splits live here
                                            //  until f_kernel runs)
static const size_t OFF_YF2 = 45514752;     // 2097152
static const size_t OFF_AFF = 47611904;     // 2048

extern "C" void kernel_launch(void* const* d_in, const int* in_sizes, int n_in,
                              void* d_out, int out_size, void* d_ws,
                              size_t ws_size, hipStream_t stream) {
  const float* xyz = (const float*)d_in[0];
  const float* feat = (const float*)d_in[1];
  const float* w1_0 = (const float*)d_in[2];
  const float* g1_0 = (const float*)d_in[3];
  const float* b1_0 = (const float*)d_in[4];
  const float* w2_0 = (const float*)d_in[5];
  const float* g2_0 = (const float*)d_in[6];
  const float* b2_0 = (const float*)d_in[7];
  const float* w1_1 = (const float*)d_in[8];
  const float* g1_1 = (const float*)d_in[9];
  const float* b1_1 = (const float*)d_in[10];
  const float* w2_1 = (const float*)d_in[11];
  const float* g2_1 = (const float*)d_in[12];
  const float* b2_1 = (const float*)d_in[13];
  const float* wf1 = (const float*)d_in[14];
  const float* gf1 = (const float*)d_in[15];
  const float* bf1 = (const float*)d_in[16];
  const float* wf2 = (const float*)d_in[17];
  const float* gf2 = (const float*)d_in[18];
  const float* bf2 = (const float*)d_in[19];

  float* out = (float*)d_out;
  float* ws = (float*)d_ws;

  int* idxfps = (int*)(ws + OFF_IDXFPS);
  float* nx = ws + OFF_NEWXYZ;
  int* idx0 = (int*)(ws + OFF_IDX0);
  int* idx1 = (int*)(ws + OFF_IDX1);
  float* y1 = ws + OFF_Y1;
  float* pmin = ws + OFF_PMIN;
  float* pmax = ws + OFF_PMAX;
  float* statp = ws + OFF_STATP;
  float* cat = ws + OFF_CONCAT;
  float* yf1 = ws + OFF_YF1;
  float* yf2 = ws + OFF_YF2;
  float* pa1 = ws + OFF_AFF;
  float* pb1 = pa1 + 128;
  float* pa2 = pb1 + 128;
  float* pb2 = pa2 + 256;
  float* paf1 = pb2 + 256;
  float* pbf1 = paf1 + 256;
  float* paf2 = pbf1 + 256;
  float* pbf2 = paf2 + 256;
  // w2 bf16 splits in the (idle until f_kernel) yf1 region:
  short* w2h0 = (short*)yf1;            // 32768 shorts each
  short* w2l0 = w2h0 + 32768;
  short* w2h1 = w2l0 + 32768;
  short* w2l1 = w2h1 + 32768;

  w2split_kernel<<<128, 256, 0, stream>>>(w2_0, w2h0, w2l0);
  w2split_kernel<<<128, 256, 0, stream>>>(w2_1, w2h1, w2l1);
  fps_kernel<<<8, 512, 0, stream>>>(xyz, idxfps, nx, out);
  bq_kernel<<<2048, 256, 0, stream>>>(xyz, nx, idx0, idx1);

  // branch 0 (r=0.1, k=16): M=131072
  g1_kernel<16><<<1024, 256, 0, stream>>>(xyz, feat, nx, idx0, w1_0, y1, statp);
  finalize_affine<<<128, 256, 0, stream>>>(statp, 1024, 1.f / 131072.f, g1_0, b1_0, pa1, pb1, 128);
  g2_kernel<16><<<1024, 256, 0, stream>>>(y1, w2h0, w2l0, pa1, pb1, pmin, pmax, statp);
  finalize_affine<<<256, 256, 0, stream>>>(statp, 1024, 1.f / 131072.f, g2_0, b2_0, pa2, pb2, 256);
  pool_concat<<<8192, 256, 0, stream>>>(pmin, pmax, pa2, pb2, cat, 0);

  // branch 1 (r=0.2, k=32): M=262144
  g1_kernel<32><<<2048, 256, 0, stream>>>(xyz, feat, nx, idx1, w1_1, y1, statp);
  finalize_affine<<<128, 256, 0, stream>>>(statp, 2048, 1.f / 262144.f, g1_1, b1_1, pa1, pb1, 128);
  g2_kernel<32><<<2048, 256, 0, stream>>>(y1, w2h1, w2l1, pa1, pb1, pmin, pmax, statp);
  finalize_affine<<<256, 256, 0, stream>>>(statp, 2048, 1.f / 262144.f, g2_1, b2_1, pa2, pb2, 256);
  pool_concat<<<8192, 256, 0, stream>>>(pmin, pmax, pa2, pb2, cat, 256);

  // fuse MLP (stats fused into f_kernel; yf1's w2-splits dead by now)
  f_kernel<false><<<dim3(128, 2), 256, 0, stream>>>(cat, wf1, nullptr, nullptr, yf1, 512, statp);
  finalize_affine<<<256, 256, 0, stream>>>(statp, 128, 1.f / 8192.f, gf1, bf1, paf1, pbf1, 256);
  f_kernel<true><<<dim3(128, 2), 256, 0, stream>>>(yf1, wf2, paf1, pbf1, yf2, 256, statp);
  finalize_affine<<<256, 256, 0, stream>>>(statp, 128, 1.f / 8192.f, gf2, bf2, paf2, pbf2, 256);
  final_write<<<8192, 256, 0, stream>>>(yf2, paf2, pbf2, out + 24576);
}